// Round 6
// baseline (878.184 us; speedup 1.0000x reference)
//
#include <hip/hip_runtime.h>
#include <cstddef>

// HSTU forward. Round 6: gemm1 128x128+XCD swizzle, attn 1024 blocks
// (descending qt) + gll16 K staging, bf16 activations (attn-out, gemm2-out),
// templated LN.
//
// ws layout (90 MB):
//   h32  f32  [8192,512]   @ 0      16 MB   residual stream
//   hbf  bf16 [8192,512]   @ 16 MB   8 MB   GEMM1 A input
//   zbf  bf16 [8192,2048]  @ 24 MB  32 MB   u|q|k|v (GEMM1 out, attn in)
//   ybf  bf16 [8192,512]   @ 56 MB   8 MB   LN1 out (GEMM2 A input)
//   yab  bf16 [8192,512]   @ 64 MB   8 MB   attn out; ALIASED by tbf (GEMM2 out)
//   W1t  bf16 [4,2048,512] @ 80 MB   8 MB   transposed bf16 weights
//   W2t  bf16 [4,512,512]  @ 88 MB   2 MB

#define D_MODEL 512
#define S_LEN 1024
#define NHEADS 8

typedef __bf16 bf16x8 __attribute__((ext_vector_type(8)));
typedef float f32x4 __attribute__((ext_vector_type(4)));
typedef unsigned short us4 __attribute__((ext_vector_type(4)));
typedef unsigned short us8 __attribute__((ext_vector_type(8)));

__device__ __forceinline__ float silu_f(float x) {
  return x / (1.f + __expf(-x));
}
__device__ __forceinline__ unsigned short f2bf(float f) {
  unsigned int u = __float_as_uint(f);
  u += 0x7FFF + ((u >> 16) & 1);   // round-to-nearest-even
  return (unsigned short)(u >> 16);
}
__device__ __forceinline__ float bf2f(unsigned short s) {
  return __uint_as_float(((unsigned int)s) << 16);
}
__device__ __forceinline__ void gll16(const void* g, void* l) {
  __builtin_amdgcn_global_load_lds(
      (const __attribute__((address_space(1))) unsigned int*)g,
      (__attribute__((address_space(3))) unsigned int*)l, 16, 0, 0);
}

// ---------------- embedding + id construction (dual f32/bf16 write) --------
__global__ __launch_bounds__(256) void embed_kernel(
    const int* __restrict__ hist_i, const int* __restrict__ hist_c,
    const int* __restrict__ hlen, const int* __restrict__ tgt_i,
    const int* __restrict__ tgt_c, const float* __restrict__ item_emb,
    const float* __restrict__ cate_emb, const float* __restrict__ seg_emb,
    float* __restrict__ h32, unsigned short* __restrict__ hbf) {
  int bs = blockIdx.x;            // b*1024 + s
  int b = bs >> 10, s = bs & 1023;
  int l = hlen[b];
  int id, cid, sg;
  if (s == l)       { id = tgt_i[b]; cid = tgt_c[b]; sg = 1; }
  else if (s < 1023){ id = hist_i[b * 1023 + s]; cid = hist_c[b * 1023 + s]; sg = 0; }
  else              { id = 0; cid = 0; sg = 0; }   // pad column
  const float* ie = item_emb + (size_t)id * D_MODEL;
  const float* ce = cate_emb + (size_t)cid * D_MODEL;
  const float* se = seg_emb + (size_t)sg * D_MODEL;
  float* hr = h32 + (size_t)bs * D_MODEL;
  unsigned short* hb = hbf + (size_t)bs * D_MODEL;
  for (int d = threadIdx.x; d < D_MODEL; d += 256) {
    float v = ie[d] + ce[d] + se[d];
    hr[d] = v;
    hb[d] = f2bf(v);
  }
}

// ---------------- weight transpose + fp32->bf16: Wt[n][k] = W[k][n] --------
__global__ __launch_bounds__(256) void transpose_kernel(
    const float* __restrict__ W, unsigned short* __restrict__ Wt,
    int K, int N) {
  const int l = blockIdx.z;
  W += (size_t)l * K * N;
  Wt += (size_t)l * K * N;
  const int n0 = blockIdx.x * 64, k0 = blockIdx.y * 64;
  __shared__ float T[64][65];
  const int tid = threadIdx.x;
  const int rr = tid >> 4, cc = (tid & 15) * 4;
#pragma unroll
  for (int p = 0; p < 4; p++) {
    const int r = rr + p * 16;
    const float4 v = *reinterpret_cast<const float4*>(&W[(size_t)(k0 + r) * N + n0 + cc]);
    T[r][cc] = v.x; T[r][cc + 1] = v.y; T[r][cc + 2] = v.z; T[r][cc + 3] = v.w;
  }
  __syncthreads();
#pragma unroll
  for (int p = 0; p < 4; p++) {
    const int r = rr + p * 16;       // n within tile
    us4 o = { f2bf(T[cc + 0][r]), f2bf(T[cc + 1][r]),
              f2bf(T[cc + 2][r]), f2bf(T[cc + 3][r]) };
    *reinterpret_cast<us4*>(&Wt[(size_t)(n0 + r) * K + k0 + cc]) = o;
  }
}

// ---------------- bf16 MFMA GEMM: C = epi(A[M,K] @ Bt[N,K]^T + bias) -------
// TMxTN tile, BK=64, 256 threads = 4 waves (2x2), wave tile (TM/2)x(TN/2).
// LDS: As/Bs [rows][64 cols] bf16, xor-swizzled 8-elem chunks.
// SWZ=1: 1D grid, XCD-aware decode (id&7 = XCD; A-stripe + B stay in L2).
template <int TM, int TN, int SWZ, int EPI_SILU, typename OutT>
__global__ __launch_bounds__(256) void mfma_gemm(
    const unsigned short* __restrict__ A, const unsigned short* __restrict__ Bt,
    const float* __restrict__ bias, OutT* __restrict__ C,
    int M, int N, int K) {
  constexpr int MI = TM / 32, NI = TN / 32;   // per-wave 16x16 tiles per dim
  __shared__ unsigned short As[TM * 64];
  __shared__ unsigned short Bs[TN * 64];
  const int tid = threadIdx.x;
  const int w = tid >> 6, lane = tid & 63, lm = lane & 15, quad = lane >> 4;
  const int wm = w & 1, wn = w >> 1;
  int m0, n0;
  if (SWZ) {
    // xcd = id&7 owns a contiguous stripe of m-blocks; n varies within xcd
    const int id = blockIdx.x;
    const int xcd = id & 7, j = id >> 3;
    const int mPerX = (M / TM) >> 3;
    m0 = (xcd * mPerX + (j % mPerX)) * TM;
    n0 = (j / mPerX) * TN;
  } else {
    m0 = blockIdx.y * TM;
    n0 = blockIdx.x * TN;
  }

  f32x4 acc[MI][NI] = {};

  for (int k0 = 0; k0 < K; k0 += 64) {
    // ---- stage A,B tiles via global_load_lds ----
#pragma unroll
    for (int p = 0; p < TM / 32; p++) {
      const int g = p * 256 + tid;         // 16B chunk id
      const int r = g >> 3;                // tile row
      const int lc = (g & 7) ^ (r & 7);    // logical k-chunk for this phys slot
      gll16(A + (size_t)(m0 + r) * K + k0 + lc * 8, &As[g * 8]);
    }
#pragma unroll
    for (int p = 0; p < TN / 32; p++) {
      const int g = p * 256 + tid;
      const int r = g >> 3;
      const int lc = (g & 7) ^ (r & 7);
      gll16(Bt + (size_t)(n0 + r) * K + k0 + lc * 8, &Bs[g * 8]);
    }
    __syncthreads();
    // ---- compute: 2 k-halves of 32 ----
#pragma unroll
    for (int ki = 0; ki < 2; ki++) {
      bf16x8 af[MI], bfr[NI];
#pragma unroll
      for (int mi = 0; mi < MI; mi++) {
        const int r = wm * (TM / 2) + mi * 16 + lm;
        const int p = (ki * 4 + quad) ^ (lm & 7);
        af[mi] = *reinterpret_cast<const bf16x8*>(&As[r * 64 + p * 8]);
      }
#pragma unroll
      for (int ni = 0; ni < NI; ni++) {
        const int r = wn * (TN / 2) + ni * 16 + lm;
        const int p = (ki * 4 + quad) ^ (lm & 7);
        bfr[ni] = *reinterpret_cast<const bf16x8*>(&Bs[r * 64 + p * 8]);
      }
#pragma unroll
      for (int mi = 0; mi < MI; mi++)
#pragma unroll
        for (int ni = 0; ni < NI; ni++)
          acc[mi][ni] = __builtin_amdgcn_mfma_f32_16x16x32_bf16(
              af[mi], bfr[ni], acc[mi][ni], 0, 0, 0);
    }
    __syncthreads();
  }

  // ---- epilogue: bias (+silu), C-layout col=lm, row=quad*4+reg ----
#pragma unroll
  for (int ni = 0; ni < NI; ni++) {
    const int n = n0 + wn * (TN / 2) + ni * 16 + lm;
    const float bv = bias[n];
#pragma unroll
    for (int mi = 0; mi < MI; mi++) {
      const int mbase = m0 + wm * (TM / 2) + mi * 16 + quad * 4;
#pragma unroll
      for (int reg = 0; reg < 4; reg++) {
        float v = acc[mi][ni][reg] + bv;
        if (EPI_SILU) v = silu_f(v);
        if constexpr (sizeof(OutT) == 2)
          C[(size_t)(mbase + reg) * N + n] = f2bf(v);
        else
          C[(size_t)(mbase + reg) * N + n] = v;
      }
    }
  }
}

// ---------------- fused causal silu-attention, S^T layout ------------------
// att = silu(q k^T + posw[2047+t-s]) * (t<=s);  y = (att @ v) * u
// z row layout (bf16): [u(512) | q(512) | k(512) | v(512)].
// Grid (16, NH, B), qt = 15 - bx (big tiles dispatch first -> tail hides).
// S^T trick: compute S^T = K Q^T (A=K rows t, B=Q rows s). C-layout gives
// lane (quad,lm): t = tt*16+quad*4+i, s = w*16+lm -> 4 t-consecutive P values
// per lane => us4 ds_write_b64 into Ps[s][t]; PV A-frag = ds_read_b128.
// Q kept in registers; K staged via gll16 into xor-swizzled rows (stride 64);
// V register-transposed into Vt (stride 72, swizzled).
#define LDR 72   // LDS row stride (u16) for Vt/Ps
__global__ __launch_bounds__(256) void attn_kernel(
    const unsigned short* __restrict__ z, const float* __restrict__ posw,
    unsigned short* __restrict__ y) {
  const int qt = 15 - (int)blockIdx.x;
  const int hh = blockIdx.y, b = blockIdx.z;
  const int s0 = qt * 64;
  __shared__ alignas(16) unsigned short Ks[64 * 64];
  __shared__ alignas(16) unsigned short Vt[64 * LDR];
  __shared__ alignas(16) unsigned short Ps[64 * LDR];
  __shared__ float bias_s[128];
  const unsigned short* zb = z + (size_t)b * S_LEN * 2048;
  const int tid = threadIdx.x;
  const int w = tid >> 6, lane = tid & 63, lm = lane & 15, quad = lane >> 4;
  const int srow = s0 + w * 16 + lm;   // this lane's q row (as B-operand n)

  // ---- Q fragments in registers (B-operand): Q[srow][ki*32+quad*8 ..+8] ----
  const bf16x8 qb0 = *reinterpret_cast<const bf16x8*>(
      zb + (size_t)srow * 2048 + 512 + hh * 64 + quad * 8);
  const bf16x8 qb1 = *reinterpret_cast<const bf16x8*>(
      zb + (size_t)srow * 2048 + 512 + hh * 64 + 32 + quad * 8);

  f32x4 O[4] = {};   // O[s 16][d 64] per wave; col=d-in-tile, row=quad*4+reg

  for (int kt = 0; kt <= qt; kt++) {
    const int t0 = kt * 64;
    __syncthreads();   // prev iter readers of Ks/Vt/bias_s done
    // ---- stage K tile (64x64) via gll16, xor-swizzled chunks ----
#pragma unroll
    for (int p = 0; p < 2; p++) {
      const int g = p * 256 + tid;       // 16B chunk id 0..511
      const int r = g >> 3;
      const int lc = (g & 7) ^ (r & 7);  // logical d-chunk for this phys slot
      gll16(zb + (size_t)(t0 + r) * 2048 + 1024 + hh * 64 + lc * 8, &Ks[g * 8]);
    }
    // ---- stage V transposed + swizzled: Vt[d][(tb ^ (d&7))*8 + ti] ----
    {
      const int t = (tid >> 4) * 4;      // 0..60
      const int d = (tid & 15) * 4;      // 0..60
      unsigned short c[4][4];
#pragma unroll
      for (int r = 0; r < 4; r++) {
        const us4 v = *reinterpret_cast<const us4*>(
            zb + (size_t)(t0 + t + r) * 2048 + 1536 + hh * 64 + d);
        c[r][0] = v.x; c[r][1] = v.y; c[r][2] = v.z; c[r][3] = v.w;
      }
      const int tb = t >> 3, ti = t & 7;
#pragma unroll
      for (int j = 0; j < 4; j++) {
        const int dd = d + j;
        us4 o = { c[0][j], c[1][j], c[2][j], c[3][j] };
        *reinterpret_cast<us4*>(&Vt[dd * LDR + ((tb ^ (dd & 7)) << 3) + ti]) = o;
      }
    }
    // ---- stage posw window: t-s in [t0-s0-63, t0-s0+63] ----
    if (tid < 128) bias_s[tid] = posw[2047 + t0 - s0 - 63 + tid];
    __syncthreads();   // staging (incl. gll16 vmcnt drain) visible to all

    // ---- S^T = K Q^T : 4 t-tiles x (16 s-cols per wave) ----
#pragma unroll
    for (int tt = 0; tt < 4; tt++) {
      const int r = tt * 16 + lm;
      const int p0 = quad ^ (r & 7);
      const int p1 = (4 + quad) ^ (r & 7);
      const bf16x8 ka0 = *reinterpret_cast<const bf16x8*>(&Ks[r * 64 + p0 * 8]);
      const bf16x8 ka1 = *reinterpret_cast<const bf16x8*>(&Ks[r * 64 + p1 * 8]);
      f32x4 st = {};
      st = __builtin_amdgcn_mfma_f32_16x16x32_bf16(ka0, qb0, st, 0, 0, 0);
      st = __builtin_amdgcn_mfma_f32_16x16x32_bf16(ka1, qb1, st, 0, 0, 0);
      // lane holds t = t0 + tt*16 + quad*4 + i,  s = srow
      const int bbase = 63 + tt * 16 + quad * 4 - w * 16 - lm;  // + i
      const int tq = t0 + tt * 16 + quad * 4;
      us4 pv;
      unsigned short* pp = (unsigned short*)&pv;
#pragma unroll
      for (int i = 0; i < 4; i++) {
        const float x = st[i] + bias_s[bbase + i];
        const float val = (tq + i <= srow) ? silu_f(x) : 0.f;
        pp[i] = f2bf(val);
      }
      // Ps[s][t]: wave-private rows [w*16, w*16+16)
      *reinterpret_cast<us4*>(&Ps[(w * 16 + lm) * LDR + tt * 16 + quad * 4]) = pv;
    }

    // ---- O += P V  (A = Ps stripe, B = Vt) ----
    const bf16x8 pa0 = *reinterpret_cast<const bf16x8*>(&Ps[(w * 16 + lm) * LDR + quad * 8]);
    const bf16x8 pa1 = *reinterpret_cast<const bf16x8*>(&Ps[(w * 16 + lm) * LDR + 32 + quad * 8]);
#pragma unroll
    for (int ct = 0; ct < 4; ct++) {
      const int d = ct * 16 + lm;
      const bf16x8 vb0 = *reinterpret_cast<const bf16x8*>(
          &Vt[d * LDR + ((quad ^ (d & 7)) << 3)]);            // tb=quad
      const bf16x8 vb1 = *reinterpret_cast<const bf16x8*>(
          &Vt[d * LDR + (((4 + quad) ^ (d & 7)) << 3)]);      // tb=4+quad
      O[ct] = __builtin_amdgcn_mfma_f32_16x16x32_bf16(pa0, vb0, O[ct], 0, 0, 0);
      O[ct] = __builtin_amdgcn_mfma_f32_16x16x32_bf16(pa1, vb1, O[ct], 0, 0, 0);
    }
  }

  // ---- epilogue: y = bf16(O * u) ----
  {
    const int sbase = s0 + w * 16 + quad * 4;
#pragma unroll
    for (int ct = 0; ct < 4; ct++) {
      const int d = ct * 16 + lm;
#pragma unroll
      for (int i = 0; i < 4; i++) {
        const int sg = sbase + i;
        const float u = bf2f(zb[(size_t)sg * 2048 + hh * 64 + d]);
        y[((size_t)(b * S_LEN + sg)) * D_MODEL + hh * 64 + d] = f2bf(O[ct][i] * u);
      }
    }
  }
}

// ---------------- layer norm: one wave per row, templated input ------------
template <typename XT>
__global__ __launch_bounds__(256) void ln_kernel(
    const XT* __restrict__ x, const float* __restrict__ res,
    const float* __restrict__ w, const float* __restrict__ bb,
    float* __restrict__ o32, unsigned short* __restrict__ obf) {
  const int wv = threadIdx.x >> 6, lane = threadIdx.x & 63;
  const size_t row = blockIdx.x * 4 + wv;
  const int c0 = lane * 8;
  float v[8];
  if constexpr (sizeof(XT) == 2) {
    const us8 u = *reinterpret_cast<const us8*>(&x[row * D_MODEL + c0]);
#pragma unroll
    for (int i = 0; i < 8; i++) v[i] = bf2f(u[i]);
  } else {
    const float4 a = *reinterpret_cast<const float4*>(&x[row * D_MODEL + c0]);
    const float4 c = *reinterpret_cast<const float4*>(&x[row * D_MODEL + c0 + 4]);
    v[0] = a.x; v[1] = a.y; v[2] = a.z; v[3] = a.w;
    v[4] = c.x; v[5] = c.y; v[6] = c.z; v[7] = c.w;
  }
  if (res) {
    const float4 r0 = *reinterpret_cast<const float4*>(&res[row * D_MODEL + c0]);
    const float4 r1 = *reinterpret_cast<const float4*>(&res[row * D_MODEL + c0 + 4]);
    v[0] += r0.x; v[1] += r0.y; v[2] += r0.z; v[3] += r0.w;
    v[4] += r1.x; v[5] += r1.y; v[6] += r1.z; v[7] += r1.w;
  }
  float s = 0.f, ss = 0.f;
#pragma unroll
  for (int i = 0; i < 8; i++) { s += v[i]; ss += v[i] * v[i]; }
#pragma unroll
  for (int off = 32; off; off >>= 1) {
    s += __shfl_down(s, off, 64);
    ss += __shfl_down(ss, off, 64);
  }
  s = __shfl(s, 0, 64);
  ss = __shfl(ss, 0, 64);
  const float mu = s * (1.f / D_MODEL);
  const float rstd = rsqrtf(ss * (1.f / D_MODEL) - mu * mu + 1e-5f);
  const float4 w0 = *reinterpret_cast<const float4*>(&w[c0]);
  const float4 w1 = *reinterpret_cast<const float4*>(&w[c0 + 4]);
  const float4 b0 = *reinterpret_cast<const float4*>(&bb[c0]);
  const float4 b1 = *reinterpret_cast<const float4*>(&bb[c0 + 4]);
  float r[8];
  r[0] = (v[0] - mu) * rstd * w0.x + b0.x;
  r[1] = (v[1] - mu) * rstd * w0.y + b0.y;
  r[2] = (v[2] - mu) * rstd * w0.z + b0.z;
  r[3] = (v[3] - mu) * rstd * w0.w + b0.w;
  r[4] = (v[4] - mu) * rstd * w1.x + b1.x;
  r[5] = (v[5] - mu) * rstd * w1.y + b1.y;
  r[6] = (v[6] - mu) * rstd * w1.z + b1.z;
  r[7] = (v[7] - mu) * rstd * w1.w + b1.w;
  if (o32) {
    *reinterpret_cast<float4*>(&o32[row * D_MODEL + c0]) = make_float4(r[0], r[1], r[2], r[3]);
    *reinterpret_cast<float4*>(&o32[row * D_MODEL + c0 + 4]) = make_float4(r[4], r[5], r[6], r[7]);
  }
  if (obf) {
    us8 q = { f2bf(r[0]), f2bf(r[1]), f2bf(r[2]), f2bf(r[3]),
              f2bf(r[4]), f2bf(r[5]), f2bf(r[6]), f2bf(r[7]) };
    *reinterpret_cast<us8*>(&obf[row * D_MODEL + c0]) = q;
  }
}

extern "C" void kernel_launch(void* const* d_in, const int* in_sizes, int n_in,
                              void* d_out, int out_size, void* d_ws, size_t ws_size,
                              hipStream_t stream) {
  const int* hist_i = (const int*)d_in[0];
  const int* hist_c = (const int*)d_in[1];
  const int* hlen   = (const int*)d_in[2];
  const int* tgt_i  = (const int*)d_in[3];
  const int* tgt_c  = (const int*)d_in[4];
  const float* item_emb = (const float*)d_in[5];
  const float* cate_emb = (const float*)d_in[6];
  const float* seg_emb  = (const float*)d_in[7];
  const float* W1   = (const float*)d_in[8];    // [4,512,2048]
  const float* b1   = (const float*)d_in[9];    // [4,2048]
  const float* W2   = (const float*)d_in[10];   // [4,512,512]
  const float* b2   = (const float*)d_in[11];   // [4,512]
  const float* ln1w = (const float*)d_in[12];
  const float* ln1b = (const float*)d_in[13];
  const float* ln2w = (const float*)d_in[14];
  const float* ln2b = (const float*)d_in[15];
  const float* posw = (const float*)d_in[16];   // [4,4095]
  const float* lnfw = (const float*)d_in[17];
  const float* lnfb = (const float*)d_in[18];
  float* out = (float*)d_out;

  char* ws = (char*)d_ws;
  float*          h32 = (float*)(ws);                         // 16 MB
  unsigned short* hbf = (unsigned short*)(ws + (16u << 20));  // 8 MB
  unsigned short* zbf = (unsigned short*)(ws + (24u << 20));  // 32 MB
  unsigned short* ybf = (unsigned short*)(ws + (56u << 20));  // 8 MB
  unsigned short* yab = (unsigned short*)(ws + (64u << 20));  // 8 MB (attn out)
  unsigned short* tbf = yab;                                  // alias: yab dead after LN1
  unsigned short* W1t = (unsigned short*)(ws + (80u << 20));  // 8 MB
  unsigned short* W2t = (unsigned short*)(ws + (88u << 20));  // 2 MB

  const int ROWS = 8 * S_LEN;  // 8192

  transpose_kernel<<<dim3(2048 / 64, 512 / 64, 4), 256, 0, stream>>>(W1, W1t, 512, 2048);
  transpose_kernel<<<dim3(512 / 64, 512 / 64, 4), 256, 0, stream>>>(W2, W2t, 512, 512);
  embed_kernel<<<ROWS, 256, 0, stream>>>(hist_i, hist_c, hlen, tgt_i, tgt_c,
                                         item_emb, cate_emb, seg_emb, h32, hbf);
  for (int l = 0; l < 4; l++) {
    // zbf = silu(h @ W1[l] + b1[l])   [8192, 2048] bf16; 128x128, XCD swizzle
    mfma_gemm<128, 128, 1, 1, unsigned short><<<1024, 256, 0, stream>>>(
        hbf, W1t + (size_t)l * 2048 * 512, b1 + (size_t)l * 2048, zbf, ROWS, 2048, 512);
    // yab = bf16((silu-att @ v) * u)  [8192, 512]; descending-qt grid
    attn_kernel<<<dim3(16, NHEADS, 8), 256, 0, stream>>>(
        zbf, posw + (size_t)l * 4095, yab);
    // ybf = LN1(yab)  (bf16 in, bf16 out)
    ln_kernel<unsigned short><<<ROWS / 4, 256, 0, stream>>>(
        yab, nullptr, ln1w + l * 512, ln1b + l * 512, nullptr, ybf);
    // tbf = bf16(ybf @ W2[l] + b2[l])  (aliases yab; yab dead after LN1)
    mfma_gemm<64, 128, 0, 0, unsigned short><<<dim3(512 / 128, ROWS / 64), 256, 0, stream>>>(
        ybf, W2t + (size_t)l * 512 * 512, b2 + (size_t)l * 512, tbf, ROWS, 512, 512);
    // h = LN2(tbf + h)  (f32 + bf16 out)
    ln_kernel<unsigned short><<<ROWS / 4, 256, 0, stream>>>(
        tbf, h32, ln2w + l * 512, ln2b + l * 512, h32, hbf);
  }
  // out = LNf(h)
  ln_kernel<float><<<ROWS / 4, 256, 0, stream>>>(h32, nullptr, lnfw, lnfb, out, nullptr);
}

// Round 7
// 807.171 us; speedup vs baseline: 1.0880x; 1.0880x over previous
//
#include <hip/hip_runtime.h>
#include <cstddef>

// HSTU forward. Round 7: R5-proven gemm1 (256x128 XCD-swizzled) + paired-qt
// attention restored; bf16 activation stream (attn-out, gemm2-out) kept.
//
// ws layout (90 MB):
//   h32  f32  [8192,512]   @ 0      16 MB   residual stream
//   hbf  bf16 [8192,512]   @ 16 MB   8 MB   GEMM1 A input
//   zbf  bf16 [8192,2048]  @ 24 MB  32 MB   u|q|k|v (GEMM1 out, attn in)
//   ybf  bf16 [8192,512]   @ 56 MB   8 MB   LN1 out (GEMM2 A input)
//   yab  bf16 [8192,512]   @ 64 MB   8 MB   attn out; ALIASED by tbf (GEMM2 out)
//   W1t  bf16 [4,2048,512] @ 80 MB   8 MB   transposed bf16 weights
//   W2t  bf16 [4,512,512]  @ 88 MB   2 MB

#define D_MODEL 512
#define S_LEN 1024
#define NHEADS 8

typedef __bf16 bf16x8 __attribute__((ext_vector_type(8)));
typedef float f32x4 __attribute__((ext_vector_type(4)));
typedef unsigned short us4 __attribute__((ext_vector_type(4)));
typedef unsigned short us8 __attribute__((ext_vector_type(8)));

__device__ __forceinline__ float silu_f(float x) {
  return x / (1.f + __expf(-x));
}
__device__ __forceinline__ unsigned short f2bf(float f) {
  unsigned int u = __float_as_uint(f);
  u += 0x7FFF + ((u >> 16) & 1);   // round-to-nearest-even
  return (unsigned short)(u >> 16);
}
__device__ __forceinline__ float bf2f(unsigned short s) {
  return __uint_as_float(((unsigned int)s) << 16);
}
__device__ __forceinline__ void gll16(const void* g, void* l) {
  __builtin_amdgcn_global_load_lds(
      (const __attribute__((address_space(1))) unsigned int*)g,
      (__attribute__((address_space(3))) unsigned int*)l, 16, 0, 0);
}

// ---------------- embedding + id construction (dual f32/bf16 write) --------
__global__ __launch_bounds__(256) void embed_kernel(
    const int* __restrict__ hist_i, const int* __restrict__ hist_c,
    const int* __restrict__ hlen, const int* __restrict__ tgt_i,
    const int* __restrict__ tgt_c, const float* __restrict__ item_emb,
    const float* __restrict__ cate_emb, const float* __restrict__ seg_emb,
    float* __restrict__ h32, unsigned short* __restrict__ hbf) {
  int bs = blockIdx.x;            // b*1024 + s
  int b = bs >> 10, s = bs & 1023;
  int l = hlen[b];
  int id, cid, sg;
  if (s == l)       { id = tgt_i[b]; cid = tgt_c[b]; sg = 1; }
  else if (s < 1023){ id = hist_i[b * 1023 + s]; cid = hist_c[b * 1023 + s]; sg = 0; }
  else              { id = 0; cid = 0; sg = 0; }   // pad column
  const float* ie = item_emb + (size_t)id * D_MODEL;
  const float* ce = cate_emb + (size_t)cid * D_MODEL;
  const float* se = seg_emb + (size_t)sg * D_MODEL;
  float* hr = h32 + (size_t)bs * D_MODEL;
  unsigned short* hb = hbf + (size_t)bs * D_MODEL;
  for (int d = threadIdx.x; d < D_MODEL; d += 256) {
    float v = ie[d] + ce[d] + se[d];
    hr[d] = v;
    hb[d] = f2bf(v);
  }
}

// ---------------- weight transpose + fp32->bf16: Wt[n][k] = W[k][n] --------
__global__ __launch_bounds__(256) void transpose_kernel(
    const float* __restrict__ W, unsigned short* __restrict__ Wt,
    int K, int N) {
  const int l = blockIdx.z;
  W += (size_t)l * K * N;
  Wt += (size_t)l * K * N;
  const int n0 = blockIdx.x * 64, k0 = blockIdx.y * 64;
  __shared__ float T[64][65];
  const int tid = threadIdx.x;
  const int rr = tid >> 4, cc = (tid & 15) * 4;
#pragma unroll
  for (int p = 0; p < 4; p++) {
    const int r = rr + p * 16;
    const float4 v = *reinterpret_cast<const float4*>(&W[(size_t)(k0 + r) * N + n0 + cc]);
    T[r][cc] = v.x; T[r][cc + 1] = v.y; T[r][cc + 2] = v.z; T[r][cc + 3] = v.w;
  }
  __syncthreads();
#pragma unroll
  for (int p = 0; p < 4; p++) {
    const int r = rr + p * 16;       // n within tile
    us4 o = { f2bf(T[cc + 0][r]), f2bf(T[cc + 1][r]),
              f2bf(T[cc + 2][r]), f2bf(T[cc + 3][r]) };
    *reinterpret_cast<us4*>(&Wt[(size_t)(n0 + r) * K + k0 + cc]) = o;
  }
}

// ---------------- bf16 MFMA GEMM: C = epi(A[M,K] @ Bt[N,K]^T + bias) -------
// TMxTN tile, BK=64, 256 threads = 4 waves (2x2), wave tile (TM/2)x(TN/2).
// LDS: As/Bs [rows][64 cols] bf16, xor-swizzled 8-elem chunks.
// SWZ=1: 1D grid, XCD-aware decode (id&7 = XCD; A-stripe + B stay in L2).
template <int TM, int TN, int SWZ, int EPI_SILU, typename OutT>
__global__ __launch_bounds__(256) void mfma_gemm(
    const unsigned short* __restrict__ A, const unsigned short* __restrict__ Bt,
    const float* __restrict__ bias, OutT* __restrict__ C,
    int M, int N, int K) {
  constexpr int MI = TM / 32, NI = TN / 32;   // per-wave 16x16 tiles per dim
  __shared__ unsigned short As[TM * 64];
  __shared__ unsigned short Bs[TN * 64];
  const int tid = threadIdx.x;
  const int w = tid >> 6, lane = tid & 63, lm = lane & 15, quad = lane >> 4;
  const int wm = w & 1, wn = w >> 1;
  int m0, n0;
  if (SWZ) {
    // xcd = id&7 owns a contiguous stripe of m-blocks; n varies within xcd
    const int id = blockIdx.x;
    const int xcd = id & 7, j = id >> 3;
    const int mPerX = (M / TM) >> 3;
    m0 = (xcd * mPerX + (j % mPerX)) * TM;
    n0 = (j / mPerX) * TN;
  } else {
    m0 = blockIdx.y * TM;
    n0 = blockIdx.x * TN;
  }

  f32x4 acc[MI][NI] = {};

  for (int k0 = 0; k0 < K; k0 += 64) {
    // ---- stage A,B tiles via global_load_lds ----
#pragma unroll
    for (int p = 0; p < TM / 32; p++) {
      const int g = p * 256 + tid;         // 16B chunk id
      const int r = g >> 3;                // tile row
      const int lc = (g & 7) ^ (r & 7);    // logical k-chunk for this phys slot
      gll16(A + (size_t)(m0 + r) * K + k0 + lc * 8, &As[g * 8]);
    }
#pragma unroll
    for (int p = 0; p < TN / 32; p++) {
      const int g = p * 256 + tid;
      const int r = g >> 3;
      const int lc = (g & 7) ^ (r & 7);
      gll16(Bt + (size_t)(n0 + r) * K + k0 + lc * 8, &Bs[g * 8]);
    }
    __syncthreads();
    // ---- compute: 2 k-halves of 32 ----
#pragma unroll
    for (int ki = 0; ki < 2; ki++) {
      bf16x8 af[MI], bfr[NI];
#pragma unroll
      for (int mi = 0; mi < MI; mi++) {
        const int r = wm * (TM / 2) + mi * 16 + lm;
        const int p = (ki * 4 + quad) ^ (lm & 7);
        af[mi] = *reinterpret_cast<const bf16x8*>(&As[r * 64 + p * 8]);
      }
#pragma unroll
      for (int ni = 0; ni < NI; ni++) {
        const int r = wn * (TN / 2) + ni * 16 + lm;
        const int p = (ki * 4 + quad) ^ (lm & 7);
        bfr[ni] = *reinterpret_cast<const bf16x8*>(&Bs[r * 64 + p * 8]);
      }
#pragma unroll
      for (int mi = 0; mi < MI; mi++)
#pragma unroll
        for (int ni = 0; ni < NI; ni++)
          acc[mi][ni] = __builtin_amdgcn_mfma_f32_16x16x32_bf16(
              af[mi], bfr[ni], acc[mi][ni], 0, 0, 0);
    }
    __syncthreads();
  }

  // ---- epilogue: bias (+silu), C-layout col=lm, row=quad*4+reg ----
#pragma unroll
  for (int ni = 0; ni < NI; ni++) {
    const int n = n0 + wn * (TN / 2) + ni * 16 + lm;
    const float bv = bias[n];
#pragma unroll
    for (int mi = 0; mi < MI; mi++) {
      const int mbase = m0 + wm * (TM / 2) + mi * 16 + quad * 4;
#pragma unroll
      for (int reg = 0; reg < 4; reg++) {
        float v = acc[mi][ni][reg] + bv;
        if (EPI_SILU) v = silu_f(v);
        if constexpr (sizeof(OutT) == 2)
          C[(size_t)(mbase + reg) * N + n] = f2bf(v);
        else
          C[(size_t)(mbase + reg) * N + n] = v;
      }
    }
  }
}

// ---------------- fused causal silu-attention, S^T layout, paired qt -------
// att = silu(q k^T + posw[2047+t-s]) * (t<=s);  y = (att @ v) * u
// z row layout (bf16): [u(512) | q(512) | k(512) | v(512)].
// Block: (qt-pair, head, b). Processes q64 tiles qt=blockIdx.x and 15-qt:
// kt-units = (qtA+1)+(qtB+1) = 17 for every block -> perfect balance.
// S^T trick: compute S^T = K Q^T (A=K rows t, B=Q rows s). C-layout gives
// lane (quad,lm): t = tt*16+quad*4+i, s = w*16+lm -> 4 t-consecutive P values
// per lane => us4 ds_write_b64 into Ps[s][t]; PV A-frag = ds_read_b128.
// Q is kept in registers (B-operand frags loaded from global once per tile).
#define LDR 72   // LDS row stride in u16 (144 B, 16B-aligned, bank-spread)
__global__ __launch_bounds__(256) void attn_kernel(
    const unsigned short* __restrict__ z, const float* __restrict__ posw,
    unsigned short* __restrict__ y) {
  const int hh = blockIdx.y, b = blockIdx.z;
  __shared__ alignas(16) unsigned short Ks[64 * LDR];
  __shared__ alignas(16) unsigned short Vt[64 * LDR];
  __shared__ alignas(16) unsigned short Ps[64 * LDR];
  __shared__ float bias_s[128];
  const unsigned short* zb = z + (size_t)b * S_LEN * 2048;
  const int tid = threadIdx.x;
  const int w = tid >> 6, lane = tid & 63, lm = lane & 15, quad = lane >> 4;

#pragma unroll
  for (int phase = 0; phase < 2; phase++) {
    const int qt = phase == 0 ? (int)blockIdx.x : 15 - (int)blockIdx.x;
    const int s0 = qt * 64;
    const int srow = s0 + w * 16 + lm;   // this lane's q row (as B-operand n)

    // ---- Q fragments in registers (B-operand): Q[srow][ki*32+quad*8 ..+8] --
    const bf16x8 qb0 = *reinterpret_cast<const bf16x8*>(
        zb + (size_t)srow * 2048 + 512 + hh * 64 + quad * 8);
    const bf16x8 qb1 = *reinterpret_cast<const bf16x8*>(
        zb + (size_t)srow * 2048 + 512 + hh * 64 + 32 + quad * 8);

    f32x4 O[4] = {};   // O[s 16][d 64] per wave; col=d-in-tile, row=quad*4+reg

    for (int kt = 0; kt <= qt; kt++) {
      const int t0 = kt * 64;
      __syncthreads();   // prev iter (or prev phase) readers of Ks/Vt done
      // ---- stage K tile (64 x 64) ----
#pragma unroll
      for (int p = 0; p < 2; p++) {
        const int g = p * 256 + tid;
        const int r = g >> 3, ch = (g & 7) * 8;
        *reinterpret_cast<us8*>(&Ks[r * LDR + ch]) =
            *reinterpret_cast<const us8*>(zb + (size_t)(t0 + r) * 2048 + 1024 + hh * 64 + ch);
      }
      // ---- stage V transposed + swizzled: Vt[d][(tb ^ (d&7))*8 + ti] ----
      {
        const int t = (tid >> 4) * 4;      // 0..60
        const int d = (tid & 15) * 4;      // 0..60
        unsigned short c[4][4];
#pragma unroll
        for (int r = 0; r < 4; r++) {
          const us4 v = *reinterpret_cast<const us4*>(
              zb + (size_t)(t0 + t + r) * 2048 + 1536 + hh * 64 + d);
          c[r][0] = v.x; c[r][1] = v.y; c[r][2] = v.z; c[r][3] = v.w;
        }
        const int tb = t >> 3, ti = t & 7;
#pragma unroll
        for (int j = 0; j < 4; j++) {
          const int dd = d + j;
          us4 o = { c[0][j], c[1][j], c[2][j], c[3][j] };
          *reinterpret_cast<us4*>(&Vt[dd * LDR + ((tb ^ (dd & 7)) << 3) + ti]) = o;
        }
      }
      // ---- stage posw window: t-s in [t0-s0-63, t0-s0+63] ----
      if (tid < 128) bias_s[tid] = posw[2047 + t0 - s0 - 63 + tid];
      __syncthreads();   // staging visible to all waves

      // ---- S^T = K Q^T : 4 t-tiles x (16 s-cols per wave) ----
#pragma unroll
      for (int tt = 0; tt < 4; tt++) {
        const bf16x8 ka0 = *reinterpret_cast<const bf16x8*>(&Ks[(tt * 16 + lm) * LDR + quad * 8]);
        const bf16x8 ka1 = *reinterpret_cast<const bf16x8*>(&Ks[(tt * 16 + lm) * LDR + 32 + quad * 8]);
        f32x4 st = {};
        st = __builtin_amdgcn_mfma_f32_16x16x32_bf16(ka0, qb0, st, 0, 0, 0);
        st = __builtin_amdgcn_mfma_f32_16x16x32_bf16(ka1, qb1, st, 0, 0, 0);
        // lane holds t = t0 + tt*16 + quad*4 + i,  s = srow
        const int bbase = 63 + tt * 16 + quad * 4 - w * 16 - lm;  // + i
        const int tq = t0 + tt * 16 + quad * 4;
        us4 pv;
        unsigned short* pp = (unsigned short*)&pv;
#pragma unroll
        for (int i = 0; i < 4; i++) {
          const float x = st[i] + bias_s[bbase + i];
          const float val = (tq + i <= srow) ? silu_f(x) : 0.f;
          pp[i] = f2bf(val);
        }
        // Ps[s][t]: wave-private rows [w*16, w*16+16)
        *reinterpret_cast<us4*>(&Ps[(w * 16 + lm) * LDR + tt * 16 + quad * 4]) = pv;
      }

      // ---- O += P V  (A = Ps stripe, B = Vt) ----
      const bf16x8 pa0 = *reinterpret_cast<const bf16x8*>(&Ps[(w * 16 + lm) * LDR + quad * 8]);
      const bf16x8 pa1 = *reinterpret_cast<const bf16x8*>(&Ps[(w * 16 + lm) * LDR + 32 + quad * 8]);
#pragma unroll
      for (int ct = 0; ct < 4; ct++) {
        const int d = ct * 16 + lm;
        const bf16x8 vb0 = *reinterpret_cast<const bf16x8*>(
            &Vt[d * LDR + ((quad ^ (d & 7)) << 3)]);            // tb=quad
        const bf16x8 vb1 = *reinterpret_cast<const bf16x8*>(
            &Vt[d * LDR + (((4 + quad) ^ (d & 7)) << 3)]);      // tb=4+quad
        O[ct] = __builtin_amdgcn_mfma_f32_16x16x32_bf16(pa0, vb0, O[ct], 0, 0, 0);
        O[ct] = __builtin_amdgcn_mfma_f32_16x16x32_bf16(pa1, vb1, O[ct], 0, 0, 0);
      }
    }

    // ---- epilogue: y = bf16(O * u) ----
    {
      const int sbase = s0 + w * 16 + quad * 4;
#pragma unroll
      for (int ct = 0; ct < 4; ct++) {
        const int d = ct * 16 + lm;
#pragma unroll
        for (int i = 0; i < 4; i++) {
          const int sg = sbase + i;
          const float u = bf2f(zb[(size_t)sg * 2048 + hh * 64 + d]);
          y[((size_t)(b * S_LEN + sg)) * D_MODEL + hh * 64 + d] = f2bf(O[ct][i] * u);
        }
      }
    }
  }
}

// ---------------- layer norm: one wave per row, templated input ------------
template <typename XT>
__global__ __launch_bounds__(256) void ln_kernel(
    const XT* __restrict__ x, const float* __restrict__ res,
    const float* __restrict__ w, const float* __restrict__ bb,
    float* __restrict__ o32, unsigned short* __restrict__ obf) {
  const int wv = threadIdx.x >> 6, lane = threadIdx.x & 63;
  const size_t row = blockIdx.x * 4 + wv;
  const int c0 = lane * 8;
  float v[8];
  if constexpr (sizeof(XT) == 2) {
    const us8 u = *reinterpret_cast<const us8*>(&x[row * D_MODEL + c0]);
#pragma unroll
    for (int i = 0; i < 8; i++) v[i] = bf2f(u[i]);
  } else {
    const float4 a = *reinterpret_cast<const float4*>(&x[row * D_MODEL + c0]);
    const float4 c = *reinterpret_cast<const float4*>(&x[row * D_MODEL + c0 + 4]);
    v[0] = a.x; v[1] = a.y; v[2] = a.z; v[3] = a.w;
    v[4] = c.x; v[5] = c.y; v[6] = c.z; v[7] = c.w;
  }
  if (res) {
    const float4 r0 = *reinterpret_cast<const float4*>(&res[row * D_MODEL + c0]);
    const float4 r1 = *reinterpret_cast<const float4*>(&res[row * D_MODEL + c0 + 4]);
    v[0] += r0.x; v[1] += r0.y; v[2] += r0.z; v[3] += r0.w;
    v[4] += r1.x; v[5] += r1.y; v[6] += r1.z; v[7] += r1.w;
  }
  float s = 0.f, ss = 0.f;
#pragma unroll
  for (int i = 0; i < 8; i++) { s += v[i]; ss += v[i] * v[i]; }
#pragma unroll
  for (int off = 32; off; off >>= 1) {
    s += __shfl_down(s, off, 64);
    ss += __shfl_down(ss, off, 64);
  }
  s = __shfl(s, 0, 64);
  ss = __shfl(ss, 0, 64);
  const float mu = s * (1.f / D_MODEL);
  const float rstd = rsqrtf(ss * (1.f / D_MODEL) - mu * mu + 1e-5f);
  const float4 w0 = *reinterpret_cast<const float4*>(&w[c0]);
  const float4 w1 = *reinterpret_cast<const float4*>(&w[c0 + 4]);
  const float4 b0 = *reinterpret_cast<const float4*>(&bb[c0]);
  const float4 b1 = *reinterpret_cast<const float4*>(&bb[c0 + 4]);
  float r[8];
  r[0] = (v[0] - mu) * rstd * w0.x + b0.x;
  r[1] = (v[1] - mu) * rstd * w0.y + b0.y;
  r[2] = (v[2] - mu) * rstd * w0.z + b0.z;
  r[3] = (v[3] - mu) * rstd * w0.w + b0.w;
  r[4] = (v[4] - mu) * rstd * w1.x + b1.x;
  r[5] = (v[5] - mu) * rstd * w1.y + b1.y;
  r[6] = (v[6] - mu) * rstd * w1.z + b1.z;
  r[7] = (v[7] - mu) * rstd * w1.w + b1.w;
  if (o32) {
    *reinterpret_cast<float4*>(&o32[row * D_MODEL + c0]) = make_float4(r[0], r[1], r[2], r[3]);
    *reinterpret_cast<float4*>(&o32[row * D_MODEL + c0 + 4]) = make_float4(r[4], r[5], r[6], r[7]);
  }
  if (obf) {
    us8 q = { f2bf(r[0]), f2bf(r[1]), f2bf(r[2]), f2bf(r[3]),
              f2bf(r[4]), f2bf(r[5]), f2bf(r[6]), f2bf(r[7]) };
    *reinterpret_cast<us8*>(&obf[row * D_MODEL + c0]) = q;
  }
}

extern "C" void kernel_launch(void* const* d_in, const int* in_sizes, int n_in,
                              void* d_out, int out_size, void* d_ws, size_t ws_size,
                              hipStream_t stream) {
  const int* hist_i = (const int*)d_in[0];
  const int* hist_c = (const int*)d_in[1];
  const int* hlen   = (const int*)d_in[2];
  const int* tgt_i  = (const int*)d_in[3];
  const int* tgt_c  = (const int*)d_in[4];
  const float* item_emb = (const float*)d_in[5];
  const float* cate_emb = (const float*)d_in[6];
  const float* seg_emb  = (const float*)d_in[7];
  const float* W1   = (const float*)d_in[8];    // [4,512,2048]
  const float* b1   = (const float*)d_in[9];    // [4,2048]
  const float* W2   = (const float*)d_in[10];   // [4,512,512]
  const float* b2   = (const float*)d_in[11];   // [4,512]
  const float* ln1w = (const float*)d_in[12];
  const float* ln1b = (const float*)d_in[13];
  const float* ln2w = (const float*)d_in[14];
  const float* ln2b = (const float*)d_in[15];
  const float* posw = (const float*)d_in[16];   // [4,4095]
  const float* lnfw = (const float*)d_in[17];
  const float* lnfb = (const float*)d_in[18];
  float* out = (float*)d_out;

  char* ws = (char*)d_ws;
  float*          h32 = (float*)(ws);                         // 16 MB
  unsigned short* hbf = (unsigned short*)(ws + (16u << 20));  // 8 MB
  unsigned short* zbf = (unsigned short*)(ws + (24u << 20));  // 32 MB
  unsigned short* ybf = (unsigned short*)(ws + (56u << 20));  // 8 MB
  unsigned short* yab = (unsigned short*)(ws + (64u << 20));  // 8 MB (attn out)
  unsigned short* tbf = yab;                                  // alias: yab dead after LN1
  unsigned short* W1t = (unsigned short*)(ws + (80u << 20));  // 8 MB
  unsigned short* W2t = (unsigned short*)(ws + (88u << 20));  // 2 MB

  const int ROWS = 8 * S_LEN;  // 8192

  transpose_kernel<<<dim3(2048 / 64, 512 / 64, 4), 256, 0, stream>>>(W1, W1t, 512, 2048);
  transpose_kernel<<<dim3(512 / 64, 512 / 64, 4), 256, 0, stream>>>(W2, W2t, 512, 512);
  embed_kernel<<<ROWS, 256, 0, stream>>>(hist_i, hist_c, hlen, tgt_i, tgt_c,
                                         item_emb, cate_emb, seg_emb, h32, hbf);
  for (int l = 0; l < 4; l++) {
    // zbf = silu(h @ W1[l] + b1[l])   [8192, 2048] bf16; 256x128, XCD swizzle
    mfma_gemm<256, 128, 1, 1, unsigned short><<<512, 256, 0, stream>>>(
        hbf, W1t + (size_t)l * 2048 * 512, b1 + (size_t)l * 2048, zbf, ROWS, 2048, 512);
    // yab = bf16((silu-att @ v) * u)  [8192, 512]; paired qt, 512 blocks
    attn_kernel<<<dim3(8, NHEADS, 8), 256, 0, stream>>>(
        zbf, posw + (size_t)l * 4095, yab);
    // ybf = LN1(yab)  (bf16 in, bf16 out)
    ln_kernel<unsigned short><<<ROWS / 4, 256, 0, stream>>>(
        yab, nullptr, ln1w + l * 512, ln1b + l * 512, nullptr, ybf);
    // tbf = bf16(ybf @ W2[l] + b2[l])  (aliases yab; yab dead after LN1)
    mfma_gemm<64, 128, 0, 0, unsigned short><<<dim3(512 / 128, ROWS / 64), 256, 0, stream>>>(
        ybf, W2t + (size_t)l * 512 * 512, b2 + (size_t)l * 512, tbf, ROWS, 512, 512);
    // h = LN2(tbf + h)  (f32 + bf16 out)
    ln_kernel<unsigned short><<<ROWS / 4, 256, 0, stream>>>(
        tbf, h32, ln2w + l * 512, ln2b + l * 512, h32, hbf);
  }
  // out = LNf(h)
  ln_kernel<float><<<ROWS / 4, 256, 0, stream>>>(h32, nullptr, lnfw, lnfb, out, nullptr);
}